// Round 15
// baseline (269.155 us; speedup 1.0000x reference)
//
#include <hip/hip_runtime.h>
#include <hip/hip_bf16.h>

#define BATCH  16384
#define SLOPE  0.2f
#define BM     16

typedef __attribute__((ext_vector_type(8))) short bf16x8;
typedef __attribute__((ext_vector_type(4))) float f32x4;
typedef __attribute__((ext_vector_type(4))) float fx4;
typedef __attribute__((ext_vector_type(2))) float fx2;

// ws layout (bf16 element offsets), weights TRANSPOSED as [N][K]; s/t contiguous.
// Pre-swizzles (16B units, same involution applied on LDS read):
//   W0T: within each 32-elem K-block, unit (k>>3)&3 stored at ((k>>3)&3) ^ (n&3)
//   W2T: within the 256B row, unit (k>>3)&15 stored at ((k>>3)&15) ^ (n&7)
#define OFF_SW0T 0         // [128][2048]
#define OFF_TW0T 262144
#define OFF_SW1T 524288    // [128][128] (unswizzled)
#define OFF_TW1T 540672
#define OFF_SW2T 557056    // [2048][128]
#define OFF_TW2T 819200

__device__ __forceinline__ unsigned short f2bf(float f) {
    unsigned int u = __float_as_uint(f);
    u += 0x7FFFu + ((u >> 16) & 1u);   // round-to-nearest-even
    return (unsigned short)(u >> 16);
}

__global__ void conv_w(const float* __restrict__ sW0, const float* __restrict__ sW1,
                       const float* __restrict__ sW2, const float* __restrict__ tW0,
                       const float* __restrict__ tW1, const float* __restrict__ tW2,
                       unsigned short* __restrict__ ws) {
    const int total = 262144 + 16384 + 262144;
    for (int i = blockIdx.x * blockDim.x + threadIdx.x; i < total;
         i += gridDim.x * blockDim.x) {
        if (i < 262144) {                    // W0 [2048][128] -> [128][2048], swz32
            int k = i >> 7, n = i & 127;
            int ks = (k & ~31) | ((((k >> 3) & 3) ^ (n & 3)) << 3) | (k & 7);
            ws[OFF_SW0T + n * 2048 + ks] = f2bf(sW0[i]);
            ws[OFF_TW0T + n * 2048 + ks] = f2bf(tW0[i]);
        } else if (i < 262144 + 16384) {     // W1 [128][128] -> transpose (no swz)
            int j = i - 262144;
            int k = j >> 7, n = j & 127;
            ws[OFF_SW1T + n * 128 + k] = f2bf(sW1[j]);
            ws[OFF_TW1T + n * 128 + k] = f2bf(tW1[j]);
        } else {                             // W2 [128][2048] -> [2048][128], swz row
            int j = i - (262144 + 16384);
            int k = j >> 11, n = j & 2047;
            int ks = ((((k >> 3) & 15) ^ (n & 7)) << 3) | (k & 7);
            ws[OFF_SW2T + n * 128 + ks] = f2bf(sW2[j]);
            ws[OFF_TW2T + n * 128 + ks] = f2bf(tW2[j]);
        }
    }
}

__global__ __launch_bounds__(256, 4) void coupling_main(
    const float* __restrict__ z,
    const float* __restrict__ s_b2,
    const float* __restrict__ t_b2,
    const unsigned short* __restrict__ ws,
    float* __restrict__ f_out,
    float* __restrict__ d_vec) {

    // LDS map (max 36864 B -> 4 blocks/CU):
    //   L0: Az dbuf [0,2K) (2x1K) | W0 dbuf [4K,36K) (2x16K)
    //   L1: HA [0,8K) | HB [8K,16K)          (L0 regions dead)
    //   L2: W2 tile [0,32K) | Dred [32K,32K+256)
    __shared__ __align__(16) unsigned char LDSbuf[36864];
    unsigned short* HA = (unsigned short*)(LDSbuf);
    unsigned short* HB = (unsigned short*)(LDSbuf + 8192);
    float* Dred = (float*)(LDSbuf + 32768);

    const int tid  = threadIdx.x;
    const int wave = tid >> 6;
    const int lane = tid & 63;
    const int l15  = lane & 15;
    const int l4   = lane >> 4;
    const int brow = blockIdx.x * BM;

    const char* wsb = (const char*)ws;
    const fx4* __restrict__ zf4 = (const fx4*)z;
    const fx2* __restrict__ zf2 = (const fx2*)z;
    fx2* __restrict__ ff2 = (fx2*)f_out;

    // ---- L0 staging helpers (tile c = lattice row c = 64 z-cols = 32 A-cols) ----
    auto ldz = [&](fx4& zr, int c) {
        const int row = tid >> 4, col16 = tid & 15;
        zr = __builtin_nontemporal_load(
            zf4 + (size_t)(brow + row) * 1024 + c * 16 + col16);
    };
    auto wrz = [&](fx4& zr, int b, int par) {
        const int row = tid >> 4, col16 = tid & 15;
        const float a0 = par ? zr.y : zr.x;
        const float a1 = par ? zr.w : zr.z;
        const unsigned int pk = (unsigned int)f2bf(a0) | ((unsigned int)f2bf(a1) << 16);
        *(unsigned int*)(LDSbuf + b * 1024 + row * 64 +
                         (((col16 >> 2) ^ (row & 3)) << 4) + (col16 & 3) * 4) = pk;
    };
    auto stageW0 = [&](int b, int c) {   // 256 g-rows x 64B (K-block c), pre-swz src
        #pragma unroll
        for (int jj = 0; jj < 4; ++jj) {
            const char* g = wsb + (size_t)(wave * 64 + jj * 16 + (lane >> 2)) * 4096
                            + c * 64 + (lane & 3) * 16;
            void* l = LDSbuf + 4096 + b * 16384 + (wave * 64 + jj * 16) * 64;
            __builtin_amdgcn_global_load_lds(
                (const __attribute__((address_space(1))) unsigned int*)g,
                (__attribute__((address_space(3))) unsigned int*)l, 16, 0, 0);
        }
    };

    f32x4 acc0[4] = {};   // [n2]
    auto cmp0 = [&](int cb) {
        const char* Az = (const char*)(LDSbuf + cb * 1024);
        const char* Wt = (const char*)(LDSbuf + 4096 + cb * 16384);
        const int row = l15;
        const bf16x8 af = *(const bf16x8*)(Az + row * 64 +
                            ((l4 * 16) ^ ((row & 3) << 4)));
        bf16x8 wf[4];
        #pragma unroll
        for (int n2 = 0; n2 < 4; ++n2) {
            const int g = wave * 64 + n2 * 16 + l15;
            wf[n2] = *(const bf16x8*)(Wt + g * 64 + ((l4 * 16) ^ ((g & 3) << 4)));
        }
        #pragma unroll
        for (int n2 = 0; n2 < 4; ++n2)
            acc0[n2] = __builtin_amdgcn_mfma_f32_16x16x32_bf16(
                af, wf[n2], acc0[n2], 0, 0, 0);
    };

    fx4 zA, zB;
    auto phase = [&](int p, int cb, fx4& zLd, fx4& zWr, int parW) {
        if (p + 1 < 64) stageW0(cb ^ 1, p + 1);
        if (p + 2 < 64) ldz(zLd, p + 2);
        cmp0(cb);
        if (p + 1 < 64) wrz(zWr, cb ^ 1, parW);
        if (p + 2 < 64)
            asm volatile("s_waitcnt lgkmcnt(0) vmcnt(1)" ::: "memory");
        else
            asm volatile("s_waitcnt lgkmcnt(0) vmcnt(0)" ::: "memory");
        __builtin_amdgcn_s_barrier();
        __builtin_amdgcn_sched_barrier(0);
    };

    // ---------------- layer 0: h0 = leaky(z_a @ W0), unified g in [0,256) ----------------
    ldz(zA, 0);
    stageW0(0, 0);
    wrz(zA, 0, 0);           // Az0 <- tile 0 (compiler waits zA)
    ldz(zB, 1);              // zB <- tile 1
    asm volatile("s_waitcnt lgkmcnt(0) vmcnt(1)" ::: "memory");
    __builtin_amdgcn_s_barrier();
    __builtin_amdgcn_sched_barrier(0);

    #pragma unroll 1
    for (int gIt = 0; gIt < 32; ++gIt) {
        phase(2 * gIt,     0, zA, zB, 1);   // writes tile 2g+1 (odd parity)
        phase(2 * gIt + 1, 1, zB, zA, 0);   // writes tile 2g+2 (even parity)
    }

    // leaky, h0 -> HA (swizzled [16][256])
    #pragma unroll
    for (int n2 = 0; n2 < 4; ++n2)
        #pragma unroll
        for (int r = 0; r < 4; ++r) {
            float v = acc0[n2][r];
            v = v > 0.0f ? v : SLOPE * v;
            const int row = l4 * 4 + r;
            const int col = wave * 64 + n2 * 16 + l15;
            HA[row * 256 + (col ^ ((row & 7) << 3))] = f2bf(v);
        }
    __syncthreads();

    // ---------------- layer 1: h1 = leaky(h0 @ W1) (direct global W1T) ----------------
    f32x4 acc1[4] = {};
    const int net1 = wave >> 1;
    #pragma unroll
    for (int k4 = 0; k4 < 4; ++k4) {
        const bf16x8 ahv = *(const bf16x8*)&HA[l15 * 256 +
            ((net1 * 128 + k4 * 32 + l4 * 8) ^ ((l15 & 7) << 3))];
        #pragma unroll
        for (int n2 = 0; n2 < 4; ++n2) {
            const bf16x8 w = *(const bf16x8*)&ws[OFF_SW1T +
                (size_t)(wave * 64 + n2 * 16 + l15) * 128 + k4 * 32 + l4 * 8];
            acc1[n2] = __builtin_amdgcn_mfma_f32_16x16x32_bf16(
                ahv, w, acc1[n2], 0, 0, 0);
        }
    }
    __syncthreads();   // HA reads done
    #pragma unroll
    for (int n2 = 0; n2 < 4; ++n2)
        #pragma unroll
        for (int r = 0; r < 4; ++r) {
            float v = acc1[n2][r];
            v = v > 0.0f ? v : SLOPE * v;
            const int row = l4 * 4 + r;
            const int col = wave * 64 + n2 * 16 + l15;
            HB[row * 256 + (col ^ ((row & 7) << 3))] = f2bf(v);
        }
    __syncthreads();

    // ---------------- layer 2 + epilogue: single 32KB W2 tile (R12 structure) ----------------
    const int par = wave >> 1;   // lattice-row parity of this wave's pairs

    // hoist A-fragments once (both nets) — HB dead after this + barrier
    bf16x8 ahs[4], aht[4];
    #pragma unroll
    for (int k4 = 0; k4 < 4; ++k4) {
        const int kc = k4 * 32 + l4 * 8;
        ahs[k4] = *(const bf16x8*)&HB[l15 * 256 + (kc ^ ((l15 & 7) << 3))];
        aht[k4] = *(const bf16x8*)&HB[l15 * 256 + ((128 + kc) ^ ((l15 & 7) << 3))];
    }
    __syncthreads();

    auto stageW2 = [&](int c2) {  // 128 rows (net*64+pair) x 256B at LDS 0, pre-swz src
        #pragma unroll
        for (int jj = 0; jj < 8; ++jj) {
            const int r  = wave * 32 + jj * 4 + (lane >> 4);
            const int pr = c2 * 64 + (r & 63);
            const char* g = wsb + (size_t)((r >> 6) ? OFF_TW2T : OFF_SW2T) * 2
                            + (size_t)pr * 256 + (lane & 15) * 16;
            void* l = LDSbuf + (wave * 32 + jj * 4) * 256;
            __builtin_amdgcn_global_load_lds(
                (const __attribute__((address_space(1))) unsigned int*)g,
                (__attribute__((address_space(3))) unsigned int*)l, 16, 0, 0);
        }
    };

    float dsum[4] = {};
    fx2 zvA[4], zvB[4];
    float sbA, tbA, sbB, tbB;
    auto ldzEp = [&](fx2 (&zv)[4], float& sb, float& tb, int c2) {
        const int j = c2 * 64 + wave * 16 + l15;
        sb = s_b2[j];
        tb = t_b2[j];
        #pragma unroll
        for (int r = 0; r < 4; ++r)
            zv[r] = __builtin_nontemporal_load(
                &zf2[(size_t)(brow + l4 * 4 + r) * 2048 + j]);
    };
    auto l2body = [&](fx2 (&zv)[4], float sb, float tb, int c2) {
        bf16x8 wfs[4], wft[4];
        #pragma unroll
        for (int k4 = 0; k4 < 4; ++k4) {
            const int rs = wave * 16 + l15;
            const int rt = 64 + wave * 16 + l15;
            const int kc = k4 * 64 + l4 * 16;
            wfs[k4] = *(const bf16x8*)(LDSbuf + rs * 256 + (kc ^ ((rs & 7) << 4)));
            wft[k4] = *(const bf16x8*)(LDSbuf + rt * 256 + (kc ^ ((rt & 7) << 4)));
        }
        f32x4 accS = {}, accT = {};
        #pragma unroll
        for (int k4 = 0; k4 < 4; ++k4) {
            accS = __builtin_amdgcn_mfma_f32_16x16x32_bf16(ahs[k4], wfs[k4], accS, 0, 0, 0);
            accT = __builtin_amdgcn_mfma_f32_16x16x32_bf16(aht[k4], wft[k4], accT, 0, 0, 0);
        }
        const int j = c2 * 64 + wave * 16 + l15;
        #pragma unroll
        for (int r = 0; r < 4; ++r) {
            const float sv = accS[r] + sb;
            const float tv = accT[r] + tb;
            const fx2 zp = zv[r];
            const float za = par ? zp.y : zp.x;
            const float zb = par ? zp.x : zp.y;
            const float fb = (zb - tv) * __expf(-sv);
            fx2 fv;
            if (par) { fv.x = fb; fv.y = za; }
            else     { fv.x = za; fv.y = fb; }
            __builtin_nontemporal_store(fv,
                &ff2[(size_t)(brow + l4 * 4 + r) * 2048 + j]);
            dsum[r] += sv;
        }
    };

    stageW2(0);
    ldzEp(zvA, sbA, tbA, 0);
    asm volatile("s_waitcnt lgkmcnt(0) vmcnt(0)" ::: "memory");
    __builtin_amdgcn_s_barrier();
    __builtin_amdgcn_sched_barrier(0);

    #pragma unroll 1
    for (int it = 0; it < 16; ++it) {
        {
            const int c2 = 2 * it;
            ldzEp(zvB, sbB, tbB, c2 + 1);         // prefetch next chunk's z/bias
            l2body(zvA, sbA, tbA, c2);
            asm volatile("s_waitcnt lgkmcnt(0)" ::: "memory");
            __builtin_amdgcn_s_barrier();         // tile reads done
            stageW2(c2 + 1);
            asm volatile("s_waitcnt lgkmcnt(0) vmcnt(0)" ::: "memory");
            __builtin_amdgcn_s_barrier();         // tile staged
            __builtin_amdgcn_sched_barrier(0);
        }
        {
            const int c2 = 2 * it + 1;
            if (c2 < 31) ldzEp(zvA, sbA, tbA, c2 + 1);
            l2body(zvB, sbB, tbB, c2);
            if (c2 < 31) {
                asm volatile("s_waitcnt lgkmcnt(0)" ::: "memory");
                __builtin_amdgcn_s_barrier();
                stageW2(c2 + 1);
                asm volatile("s_waitcnt lgkmcnt(0) vmcnt(0)" ::: "memory");
                __builtin_amdgcn_s_barrier();
                __builtin_amdgcn_sched_barrier(0);
            }
        }
    }

    // ---------------- d reduction ----------------
    __syncthreads();
    #pragma unroll
    for (int r = 0; r < 4; ++r) {
        float v = dsum[r];
        v += __shfl_xor(v, 1);
        v += __shfl_xor(v, 2);
        v += __shfl_xor(v, 4);
        v += __shfl_xor(v, 8);
        if (l15 == 0) Dred[wave * 16 + l4 * 4 + r] = v;
    }
    __syncthreads();
    if (tid < BM)
        d_vec[brow + tid] = Dred[tid] + Dred[16 + tid] + Dred[32 + tid] + Dred[48 + tid];
}

extern "C" void kernel_launch(void* const* d_in, const int* in_sizes, int n_in,
                              void* d_out, int out_size, void* d_ws, size_t ws_size,
                              hipStream_t stream) {
    const float* z   = (const float*)d_in[0];
    const float* sW0 = (const float*)d_in[1];
    const float* sW1 = (const float*)d_in[2];
    const float* sW2 = (const float*)d_in[3];
    const float* sb2 = (const float*)d_in[4];
    const float* tW0 = (const float*)d_in[5];
    const float* tW1 = (const float*)d_in[6];
    const float* tW2 = (const float*)d_in[7];
    const float* tb2 = (const float*)d_in[8];

    float* fout = (float*)d_out;
    float* dvec = fout + (size_t)BATCH * 4096;
    unsigned short* ws = (unsigned short*)d_ws;

    hipLaunchKernelGGL(conv_w, dim3(512), dim3(256), 0, stream,
                       sW0, sW1, sW2, tW0, tW1, tW2, ws);
    hipLaunchKernelGGL(coupling_main, dim3(BATCH / BM), dim3(256), 0, stream,
                       z, sb2, tb2, ws, fout, dvec);
}

// Round 16
// 188.527 us; speedup vs baseline: 1.4277x; 1.4277x over previous
//
#include <hip/hip_runtime.h>
#include <hip/hip_bf16.h>

#define BATCH  16384
#define SLOPE  0.2f
#define BM     32

typedef __attribute__((ext_vector_type(8))) short bf16x8;
typedef __attribute__((ext_vector_type(4))) float f32x4;
typedef __attribute__((ext_vector_type(4))) float fx4;
typedef __attribute__((ext_vector_type(2))) float fx2;

// ws layout (bf16 element offsets), weights TRANSPOSED as [N][K]; s/t contiguous.
// W0T and W2T rows are PRE-SWIZZLED in 16B units: unit u of row n at u ^ (n&7)
// (within each 128B chunk for W0T; within the 256B row for W2T).
#define OFF_SW0T 0         // [128][2048]
#define OFF_TW0T 262144
#define OFF_SW1T 524288    // [128][128] (unswizzled)
#define OFF_TW1T 540672
#define OFF_SW2T 557056    // [2048][128]
#define OFF_TW2T 819200

__device__ __forceinline__ unsigned short f2bf(float f) {
    unsigned int u = __float_as_uint(f);
    u += 0x7FFFu + ((u >> 16) & 1u);   // round-to-nearest-even
    return (unsigned short)(u >> 16);
}

__global__ void conv_w(const float* __restrict__ sW0, const float* __restrict__ sW1,
                       const float* __restrict__ sW2, const float* __restrict__ tW0,
                       const float* __restrict__ tW1, const float* __restrict__ tW2,
                       unsigned short* __restrict__ ws) {
    const int total = 262144 + 16384 + 262144;
    for (int i = blockIdx.x * blockDim.x + threadIdx.x; i < total;
         i += gridDim.x * blockDim.x) {
        if (i < 262144) {                    // W0 [2048][128] -> [128][2048], swz
            int k = i >> 7, n = i & 127;
            int ks = (k & ~63) | ((((k >> 3) & 7) ^ (n & 7)) << 3) | (k & 7);
            ws[OFF_SW0T + n * 2048 + ks] = f2bf(sW0[i]);
            ws[OFF_TW0T + n * 2048 + ks] = f2bf(tW0[i]);
        } else if (i < 262144 + 16384) {     // W1 [128][128] -> transpose (no swz)
            int j = i - 262144;
            int k = j >> 7, n = j & 127;
            ws[OFF_SW1T + n * 128 + k] = f2bf(sW1[j]);
            ws[OFF_TW1T + n * 128 + k] = f2bf(tW1[j]);
        } else {                             // W2 [128][2048] -> [2048][128], swz
            int j = i - (262144 + 16384);
            int k = j >> 11, n = j & 2047;
            int ks = ((((k >> 3) & 15) ^ (n & 7)) << 3) | (k & 7);
            ws[OFF_SW2T + n * 128 + ks] = f2bf(sW2[j]);
            ws[OFF_TW2T + n * 128 + ks] = f2bf(tW2[j]);
        }
    }
}

__global__ __launch_bounds__(256, 2) void coupling_main(
    const float* __restrict__ z,
    const float* __restrict__ s_b2,
    const float* __restrict__ t_b2,
    const unsigned short* __restrict__ ws,
    float* __restrict__ f_out,
    float* __restrict__ d_vec) {

    // LDS map:
    //   L0: Az dbuf [0,8K) (2x4K) | W0 dbuf [8K,72K) (2x32K)
    //   L1: HA [8K,24K) | HB [24K,40K)      (L0 regions dead)
    //   L2: W2 dbuf [0,64K) | Dred [64K,64K+512)
    __shared__ __align__(16) unsigned char LDSbuf[73728];
    unsigned short* HA = (unsigned short*)(LDSbuf + 8192);
    unsigned short* HB = (unsigned short*)(LDSbuf + 24576);
    float* Dred = (float*)(LDSbuf + 65536);

    const int tid  = threadIdx.x;
    const int wave = tid >> 6;
    const int lane = tid & 63;
    const int l15  = lane & 15;
    const int l4   = lane >> 4;
    const int brow = blockIdx.x * BM;

    const char* wsb = (const char*)ws;
    const fx4* __restrict__ zf4 = (const fx4*)z;
    const fx2* __restrict__ zf2 = (const fx2*)z;
    fx2* __restrict__ ff2 = (fx2*)f_out;

    // ---- L0 staging helpers ----
    auto ldzTo = [&](fx4 (&zr)[4], int c) {
        #pragma unroll
        for (int q = 0; q < 4; ++q) {
            const int f = tid + 256 * q;
            const int row = f >> 5, col16 = f & 31;
            zr[q] = __builtin_nontemporal_load(
                zf4 + (size_t)(brow + row) * 1024 + c * 32 + col16);
        }
    };
    auto wrzFrom = [&](fx4 (&zr)[4], int b) {
        #pragma unroll
        for (int q = 0; q < 4; ++q) {
            const int f = tid + 256 * q;
            const int row = f >> 5, col16 = f & 31;
            const int par = (col16 >> 4) & 1;
            const float a0 = par ? zr[q].y : zr[q].x;
            const float a1 = par ? zr[q].w : zr[q].z;
            const unsigned int pk = (unsigned int)f2bf(a0) | ((unsigned int)f2bf(a1) << 16);
            *(unsigned int*)(LDSbuf + b * 4096 + row * 128 +
                             (((col16 >> 2) ^ (row & 7)) << 4) + (col16 & 3) * 4) = pk;
        }
    };
    auto stageW0 = [&](int b, int c) {   // 256 g-rows x 128B (K-chunk c), pre-swz src
        #pragma unroll
        for (int jj = 0; jj < 8; ++jj) {
            const char* g = wsb + (size_t)(wave * 64 + jj * 8 + (lane >> 3)) * 4096
                            + c * 128 + (lane & 7) * 16;
            void* l = LDSbuf + 8192 + b * 32768 + (wave * 64 + jj * 8) * 128;
            __builtin_amdgcn_global_load_lds(
                (const __attribute__((address_space(1))) unsigned int*)g,
                (__attribute__((address_space(3))) unsigned int*)l, 16, 0, 0);
        }
    };

    f32x4 acc0[2][4] = {};   // [m][n2]
    auto cmp0 = [&](int cb) {
        const char* Az = (const char*)(LDSbuf + cb * 4096);
        const char* Wt = (const char*)(LDSbuf + 8192 + cb * 32768);
        bf16x8 af[2][2], wf[4][2];
        #pragma unroll
        for (int m = 0; m < 2; ++m)
            #pragma unroll
            for (int k2 = 0; k2 < 2; ++k2) {
                const int row = m * 16 + l15;
                af[m][k2] = *(const bf16x8*)(Az + row * 128 +
                              ((k2 * 64 + l4 * 16) ^ ((row & 7) << 4)));
            }
        #pragma unroll
        for (int n2 = 0; n2 < 4; ++n2)
            #pragma unroll
            for (int k2 = 0; k2 < 2; ++k2) {
                const int g = wave * 64 + n2 * 16 + l15;
                wf[n2][k2] = *(const bf16x8*)(Wt + g * 128 +
                               ((k2 * 64 + l4 * 16) ^ ((g & 7) << 4)));
            }
        #pragma unroll
        for (int n2 = 0; n2 < 4; ++n2)
            #pragma unroll
            for (int k2 = 0; k2 < 2; ++k2)
                #pragma unroll
                for (int m = 0; m < 2; ++m)
                    acc0[m][n2] = __builtin_amdgcn_mfma_f32_16x16x32_bf16(
                        af[m][k2], wf[n2][k2], acc0[m][n2], 0, 0, 0);
    };

    fx4 zA[4], zB[4];
    auto phase = [&](int p, int cb, fx4 (&zLd)[4], fx4 (&zWr)[4]) {
        if (p + 1 < 32) stageW0(cb ^ 1, p + 1);
        if (p + 2 < 32) ldzTo(zLd, p + 2);
        cmp0(cb);
        if (p + 1 < 32) wrzFrom(zWr, cb ^ 1);
        if (p + 2 < 32)
            asm volatile("s_waitcnt lgkmcnt(0) vmcnt(4)" ::: "memory");
        else
            asm volatile("s_waitcnt lgkmcnt(0) vmcnt(0)" ::: "memory");
        __builtin_amdgcn_s_barrier();
        __builtin_amdgcn_sched_barrier(0);
    };

    // ---------------- layer 0: h0 = leaky(z_a @ W0), unified g in [0,256) ----------------
    ldzTo(zB, 0);
    stageW0(0, 0);
    wrzFrom(zB, 0);          // Az0 <- tile 0
    ldzTo(zB, 1);            // zB <- tile 1
    asm volatile("s_waitcnt lgkmcnt(0) vmcnt(4)" ::: "memory");
    __builtin_amdgcn_s_barrier();
    __builtin_amdgcn_sched_barrier(0);

    #pragma unroll 1
    for (int gIt = 0; gIt < 16; ++gIt) {
        phase(2 * gIt,     0, zA, zB);
        phase(2 * gIt + 1, 1, zB, zA);
    }

    // leaky, h0 -> HA (swizzled [32][256])
    #pragma unroll
    for (int m = 0; m < 2; ++m)
        #pragma unroll
        for (int n2 = 0; n2 < 4; ++n2)
            #pragma unroll
            for (int r = 0; r < 4; ++r) {
                float v = acc0[m][n2][r];
                v = v > 0.0f ? v : SLOPE * v;
                const int row = m * 16 + l4 * 4 + r;
                const int col = wave * 64 + n2 * 16 + l15;
                HA[row * 256 + (col ^ ((row & 7) << 3))] = f2bf(v);
            }
    __syncthreads();

    // ---------------- layer 1: h1 = leaky(h0 @ W1) (direct global W1T) ----------------
    f32x4 acc1[2][4] = {};
    const int net1 = wave >> 1;
    #pragma unroll
    for (int k4 = 0; k4 < 4; ++k4) {
        bf16x8 ahv[2];
        #pragma unroll
        for (int m = 0; m < 2; ++m) {
            const int row = m * 16 + l15;
            ahv[m] = *(const bf16x8*)&HA[row * 256 +
                       ((net1 * 128 + k4 * 32 + l4 * 8) ^ ((row & 7) << 3))];
        }
        #pragma unroll
        for (int n2 = 0; n2 < 4; ++n2) {
            const bf16x8 w = *(const bf16x8*)&ws[OFF_SW1T +
                (size_t)(wave * 64 + n2 * 16 + l15) * 128 + k4 * 32 + l4 * 8];
            #pragma unroll
            for (int m = 0; m < 2; ++m)
                acc1[m][n2] = __builtin_amdgcn_mfma_f32_16x16x32_bf16(
                    ahv[m], w, acc1[m][n2], 0, 0, 0);
        }
    }
    __syncthreads();   // HA reads done
    #pragma unroll
    for (int m = 0; m < 2; ++m)
        #pragma unroll
        for (int n2 = 0; n2 < 4; ++n2)
            #pragma unroll
            for (int r = 0; r < 4; ++r) {
                float v = acc1[m][n2][r];
                v = v > 0.0f ? v : SLOPE * v;
                const int row = m * 16 + l4 * 4 + r;
                const int col = wave * 64 + n2 * 16 + l15;
                HB[row * 256 + (col ^ ((row & 7) << 3))] = f2bf(v);
            }
    __syncthreads();

    // ---------------- layer 2 + epilogue: W2 dbuf, z prefetched a chunk ahead ----------------
    const int par = wave >> 1;   // lattice-row parity of this wave's pairs

    // hoist A-fragments once (both nets)
    bf16x8 ahs[2][4], aht[2][4];   // [m][k4]
    #pragma unroll
    for (int m = 0; m < 2; ++m)
        #pragma unroll
        for (int k4 = 0; k4 < 4; ++k4) {
            const int row = m * 16 + l15;
            const int kc = k4 * 32 + l4 * 8;
            ahs[m][k4] = *(const bf16x8*)&HB[row * 256 + (kc ^ ((row & 7) << 3))];
            aht[m][k4] = *(const bf16x8*)&HB[row * 256 + ((128 + kc) ^ ((row & 7) << 3))];
        }
    __syncthreads();   // HB region overlaps W2 bufs — all reads done first

    auto stageW2 = [&](int b, int c2) {  // 128 rows (net*64+pair) x 256B, pre-swz src
        #pragma unroll
        for (int jj = 0; jj < 8; ++jj) {
            const int r  = wave * 32 + jj * 4 + (lane >> 4);
            const int pr = c2 * 64 + (r & 63);
            const char* g = wsb + (size_t)((r >> 6) ? OFF_TW2T : OFF_SW2T) * 2
                            + (size_t)pr * 256 + (lane & 15) * 16;
            void* l = LDSbuf + b * 32768 + (wave * 32 + jj * 4) * 256;
            __builtin_amdgcn_global_load_lds(
                (const __attribute__((address_space(1))) unsigned int*)g,
                (__attribute__((address_space(3))) unsigned int*)l, 16, 0, 0);
        }
    };

    float dsum[2][4] = {};

    // z/bias prefetch named sets (static indexing, rule #20)
    fx2 zvA[2][4], zvB[2][4];
    float sbA, tbA, sbB, tbB;
    auto ldzEp = [&](fx2 (&zv)[2][4], float& sb, float& tb, int c2) {
        const int j = c2 * 64 + wave * 16 + l15;
        sb = s_b2[j];
        tb = t_b2[j];
        #pragma unroll
        for (int m = 0; m < 2; ++m)
            #pragma unroll
            for (int r = 0; r < 4; ++r)
                zv[m][r] = __builtin_nontemporal_load(
                    &zf2[(size_t)(brow + m * 16 + l4 * 4 + r) * 2048 + j]);
    };

    auto l2body = [&](fx2 (&zv)[2][4], float sb, float tb, int c2, int cb) {
        bf16x8 wfs[4], wft[4];
        #pragma unroll
        for (int k4 = 0; k4 < 4; ++k4) {
            const int rs = wave * 16 + l15;
            const int rt = 64 + wave * 16 + l15;
            const int kc = k4 * 64 + l4 * 16;
            wfs[k4] = *(const bf16x8*)(LDSbuf + cb * 32768 + rs * 256 + (kc ^ ((rs & 7) << 4)));
            wft[k4] = *(const bf16x8*)(LDSbuf + cb * 32768 + rt * 256 + (kc ^ ((rt & 7) << 4)));
        }
        f32x4 acc2[2][2] = {};   // [net][m]
        #pragma unroll
        for (int k4 = 0; k4 < 4; ++k4)
            #pragma unroll
            for (int m = 0; m < 2; ++m) {
                acc2[0][m] = __builtin_amdgcn_mfma_f32_16x16x32_bf16(
                    ahs[m][k4], wfs[k4], acc2[0][m], 0, 0, 0);
                acc2[1][m] = __builtin_amdgcn_mfma_f32_16x16x32_bf16(
                    aht[m][k4], wft[k4], acc2[1][m], 0, 0, 0);
            }
        const int j = c2 * 64 + wave * 16 + l15;
        #pragma unroll
        for (int m = 0; m < 2; ++m)
            #pragma unroll
            for (int r = 0; r < 4; ++r) {
                const float sv = acc2[0][m][r] + sb;
                const float tv = acc2[1][m][r] + tb;
                const fx2 zp = zv[m][r];
                const float za = par ? zp.y : zp.x;
                const float zb = par ? zp.x : zp.y;
                const float fb = (zb - tv) * __expf(-sv);
                fx2 fv;
                if (par) { fv.x = fb; fv.y = za; }
                else     { fv.x = za; fv.y = fb; }
                __builtin_nontemporal_store(fv,
                    &ff2[(size_t)(brow + m * 16 + l4 * 4 + r) * 2048 + j]);
                dsum[m][r] += sv;
            }
    };

    // prologue: stage tile 0 + z(0); single drain
    stageW2(0, 0);
    ldzEp(zvA, sbA, tbA, 0);
    __syncthreads();

    // Per chunk: issue z(c2+1) prefetch FIRST, then stage W2(c2+1); body runs
    // from registers (no mid-chunk vmem wait); the end-of-chunk __syncthreads
    // pays only the residual stage/prefetch latency after the body.
    #pragma unroll 1
    for (int it = 0; it < 16; ++it) {
        {
            const int c2 = 2 * it;
            ldzEp(zvB, sbB, tbB, c2 + 1);
            stageW2(1, c2 + 1);
            l2body(zvA, sbA, tbA, c2, 0);
            __syncthreads();
        }
        {
            const int c2 = 2 * it + 1;
            if (c2 < 31) {
                ldzEp(zvA, sbA, tbA, c2 + 1);
                stageW2(0, c2 + 1);
            }
            l2body(zvB, sbB, tbB, c2, 1);
            __syncthreads();
        }
    }

    // ---------------- d reduction ----------------
    #pragma unroll
    for (int m = 0; m < 2; ++m)
        #pragma unroll
        for (int r = 0; r < 4; ++r) {
            float v = dsum[m][r];
            v += __shfl_xor(v, 1);
            v += __shfl_xor(v, 2);
            v += __shfl_xor(v, 4);
            v += __shfl_xor(v, 8);
            if (l15 == 0) Dred[wave * 32 + m * 16 + l4 * 4 + r] = v;
        }
    __syncthreads();
    if (tid < BM)
        d_vec[brow + tid] = Dred[tid] + Dred[32 + tid] + Dred[64 + tid] + Dred[96 + tid];
}

extern "C" void kernel_launch(void* const* d_in, const int* in_sizes, int n_in,
                              void* d_out, int out_size, void* d_ws, size_t ws_size,
                              hipStream_t stream) {
    const float* z   = (const float*)d_in[0];
    const float* sW0 = (const float*)d_in[1];
    const float* sW1 = (const float*)d_in[2];
    const float* sW2 = (const float*)d_in[3];
    const float* sb2 = (const float*)d_in[4];
    const float* tW0 = (const float*)d_in[5];
    const float* tW1 = (const float*)d_in[6];
    const float* tW2 = (const float*)d_in[7];
    const float* tb2 = (const float*)d_in[8];

    float* fout = (float*)d_out;
    float* dvec = fout + (size_t)BATCH * 4096;
    unsigned short* ws = (unsigned short*)d_ws;

    hipLaunchKernelGGL(conv_w, dim3(512), dim3(256), 0, stream,
                       sW0, sW1, sW2, tW0, tW1, tW2, ws);
    hipLaunchKernelGGL(coupling_main, dim3(BATCH / BM), dim3(256), 0, stream,
                       z, sb2, tb2, ws, fout, dvec);
}